// Round 1
// baseline (620.851 us; speedup 1.0000x reference)
//
#include <hip/hip_runtime.h>

#define N_TOK 2048
#define DMODEL 1024
#define NH 16
#define NKV 4
#define HDIM 64
#define QK_SCALE 0.125f
#define LOG2E 1.4426950408889634f

__device__ __forceinline__ float fexp2(float x) { return __builtin_amdgcn_exp2f(x); }

// C(M x NC) = A(M x K) @ B(K x NC), row-major fp32, optional fused RoPE epilogue.
// Block: 256 threads, tile 64x64, k-step 16, 4x4 acc per thread.
template<bool ROPE>
__global__ __launch_bounds__(256, 4) void gemm64(
    const float* __restrict__ A, const float* __restrict__ B, float* __restrict__ C,
    int K, int NC,
    const float* __restrict__ fc, const float* __restrict__ fs)
{
    __shared__ float Ast[16][68];  // [k][m] (A transposed)
    __shared__ float Bs[16][68];   // [k][n]
    const int t  = threadIdx.x;
    const int m0 = blockIdx.x * 64;
    const int n0 = blockIdx.y * 64;
    const int tx = t & 15;         // col group
    const int ty = t >> 4;         // row group (also B load row, 0..15)
    const int arow = t >> 2;       // A load row 0..63
    const int ac   = (t & 3) << 2; // A load k-chunk
    const int bc   = tx << 2;      // col offset

    float acc[4][4] = {};

    for (int k0 = 0; k0 < K; k0 += 16) {
        float4 av = *(const float4*)(A + (size_t)(m0 + arow) * K + (k0 + ac));
        float4 bv = *(const float4*)(B + (size_t)(k0 + ty) * NC + (n0 + bc));
        __syncthreads();
        Ast[ac + 0][arow] = av.x;
        Ast[ac + 1][arow] = av.y;
        Ast[ac + 2][arow] = av.z;
        Ast[ac + 3][arow] = av.w;
        *(float4*)&Bs[ty][bc] = bv;
        __syncthreads();
#pragma unroll
        for (int kk = 0; kk < 16; ++kk) {
            float4 a4 = *(const float4*)&Ast[kk][ty << 2];
            float4 b4 = *(const float4*)&Bs[kk][bc];
            float a[4] = {a4.x, a4.y, a4.z, a4.w};
            float b[4] = {b4.x, b4.y, b4.z, b4.w};
#pragma unroll
            for (int i = 0; i < 4; ++i)
#pragma unroll
                for (int j = 0; j < 4; ++j)
                    acc[i][j] += a[i] * b[j];
        }
    }

    const int rbase = m0 + (ty << 2);
    const int cg = n0 + bc;
#pragma unroll
    for (int i = 0; i < 4; ++i) {
        const int r = rbase + i;
        float4 ov;
        if (ROPE) {
            // cols cg..cg+3 lie within one head (cg % 4 == 0, HDIM % 4 == 0)
            const int p0 = (cg & (HDIM - 1)) >> 1;
            const float c0f = fc[r * (HDIM / 2) + p0];
            const float s0f = fs[r * (HDIM / 2) + p0];
            const float c1f = fc[r * (HDIM / 2) + p0 + 1];
            const float s1f = fs[r * (HDIM / 2) + p0 + 1];
            ov.x = acc[i][0] * c0f - acc[i][1] * s0f;
            ov.y = acc[i][0] * s0f + acc[i][1] * c0f;
            ov.z = acc[i][2] * c1f - acc[i][3] * s1f;
            ov.w = acc[i][2] * s1f + acc[i][3] * c1f;
        } else {
            ov.x = acc[i][0]; ov.y = acc[i][1]; ov.z = acc[i][2]; ov.w = acc[i][3];
        }
        *(float4*)(C + (size_t)r * NC + cg) = ov;
    }
}

// Flash-style attention, fp32. Grid: (N/64, NH). Block: 256 threads.
// Per block: 64 q-rows of one head; loop over 32 k-tiles of 64 keys.
// LDS: Qt [d][r] (Q^T, scaled), KV union (K^T [d][m] during S; V [m][d] during PV),
//      Pt [m][r] (P^T), redm/reds row-reduction scratch.  Total ~60.9 KB.
__global__ __launch_bounds__(256, 2) void attn64(
    const float* __restrict__ Q, const float* __restrict__ Kg, const float* __restrict__ Vg,
    float* __restrict__ O)
{
    __shared__ float Qt[64][68];
    __shared__ float KV[64][68];
    __shared__ float Pt[64][68];
    __shared__ float redm[64][17];
    __shared__ float reds[64][17];

    const int t   = threadIdx.x;
    const int n0  = blockIdx.x * 64;
    const int h   = blockIdx.y;
    const int kvh = h >> 2;           // REPEATS = 4
    const int tr  = t & 15, tm = t >> 4;
    const int r0  = tr << 2;          // q-row group
    const int c0  = tm << 2;          // key group (S phase) / dim group (PV phase)
    const int lrow = t >> 2;          // load row 0..63
    const int ldc  = (t & 3) << 4;    // load dim chunk start (16 dims)

    // Load Q tile transposed, folding softmax scale * log2(e)
    {
        const float* qp = Q + (size_t)(n0 + lrow) * (NH * HDIM) + h * HDIM + ldc;
        const float sc = QK_SCALE * LOG2E;
#pragma unroll
        for (int i = 0; i < 4; ++i) {
            float4 qv = *(const float4*)(qp + 4 * i);
            Qt[ldc + 4 * i + 0][lrow] = qv.x * sc;
            Qt[ldc + 4 * i + 1][lrow] = qv.y * sc;
            Qt[ldc + 4 * i + 2][lrow] = qv.z * sc;
            Qt[ldc + 4 * i + 3][lrow] = qv.w * sc;
        }
    }

    float m_run[4], l_run[4], o_acc[4][4];
#pragma unroll
    for (int i = 0; i < 4; ++i) {
        m_run[i] = -1e30f;
        l_run[i] = 0.f;
#pragma unroll
        for (int j = 0; j < 4; ++j) o_acc[i][j] = 0.f;
    }

    const int NT = N_TOK / 64;
    // Preload K/V tile 0 into registers
    float4 kreg[4], vreg[4];
    {
        const float* kp = Kg + (size_t)lrow * (NKV * HDIM) + kvh * HDIM + ldc;
        const float* vp = Vg + (size_t)lrow * (NKV * HDIM) + kvh * HDIM + ldc;
#pragma unroll
        for (int i = 0; i < 4; ++i) {
            kreg[i] = *(const float4*)(kp + 4 * i);
            vreg[i] = *(const float4*)(vp + 4 * i);
        }
    }

    for (int kt = 0; kt < NT; ++kt) {
        __syncthreads();  // b1: prev PV reads of KV(V) and Pt done
        // K -> LDS transposed [d][m]
#pragma unroll
        for (int i = 0; i < 4; ++i) {
            KV[ldc + 4 * i + 0][lrow] = kreg[i].x;
            KV[ldc + 4 * i + 1][lrow] = kreg[i].y;
            KV[ldc + 4 * i + 2][lrow] = kreg[i].z;
            KV[ldc + 4 * i + 3][lrow] = kreg[i].w;
        }
        __syncthreads();  // b2: K (and Qt, first iter) visible
        // Prefetch next K (latency hidden behind S compute)
        if (kt + 1 < NT) {
            const float* kp2 = Kg + (size_t)((kt + 1) * 64 + lrow) * (NKV * HDIM) + kvh * HDIM + ldc;
#pragma unroll
            for (int i = 0; i < 4; ++i) kreg[i] = *(const float4*)(kp2 + 4 * i);
        }
        // S = (scaled Q) K^T : s[i][j] for rows r0+i, keys c0+j
        float s[4][4] = {};
#pragma unroll 8
        for (int d = 0; d < 64; ++d) {
            float4 q4 = *(const float4*)&Qt[d][r0];
            float4 k4 = *(const float4*)&KV[d][c0];
            float a[4] = {q4.x, q4.y, q4.z, q4.w};
            float b[4] = {k4.x, k4.y, k4.z, k4.w};
#pragma unroll
            for (int i = 0; i < 4; ++i)
#pragma unroll
                for (int j = 0; j < 4; ++j)
                    s[i][j] += a[i] * b[j];
        }
        // local row max
#pragma unroll
        for (int i = 0; i < 4; ++i) {
            float lm = fmaxf(fmaxf(s[i][0], s[i][1]), fmaxf(s[i][2], s[i][3]));
            redm[r0 + i][tm] = lm;
        }
        __syncthreads();  // b3: redm visible; all S reads of KV done
        // V -> LDS natural [m][d] (overwrites K region)
#pragma unroll
        for (int i = 0; i < 4; ++i)
            *(float4*)&KV[lrow][ldc + 4 * i] = vreg[i];
        // Prefetch next V (latency hidden behind softmax math)
        if (kt + 1 < NT) {
            const float* vp2 = Vg + (size_t)((kt + 1) * 64 + lrow) * (NKV * HDIM) + kvh * HDIM + ldc;
#pragma unroll
            for (int i = 0; i < 4; ++i) vreg[i] = *(const float4*)(vp2 + 4 * i);
        }
        // tile row max -> m_new, alpha, p, row sums
        float alpha[4], p[4][4];
#pragma unroll
        for (int i = 0; i < 4; ++i) {
            float tmax = redm[r0 + i][0];
#pragma unroll
            for (int jj = 1; jj < 16; ++jj) tmax = fmaxf(tmax, redm[r0 + i][jj]);
            float mnew = fmaxf(m_run[i], tmax);
            alpha[i] = fexp2(m_run[i] - mnew);
            m_run[i] = mnew;
            float lsum = 0.f;
#pragma unroll
            for (int j = 0; j < 4; ++j) {
                p[i][j] = fexp2(s[i][j] - mnew);
                lsum += p[i][j];
            }
            reds[r0 + i][tm] = lsum;
        }
        // P -> LDS transposed [m][r]
#pragma unroll
        for (int j = 0; j < 4; ++j)
#pragma unroll
            for (int i = 0; i < 4; ++i)
                Pt[c0 + j][r0 + i] = p[i][j];
        __syncthreads();  // b4: reds, Pt, V visible
        // fold tile sums; rescale accumulator
#pragma unroll
        for (int i = 0; i < 4; ++i) {
            float tsum = 0.f;
#pragma unroll
            for (int jj = 0; jj < 16; ++jj) tsum += reds[r0 + i][jj];
            l_run[i] = l_run[i] * alpha[i] + tsum;
#pragma unroll
            for (int j = 0; j < 4; ++j) o_acc[i][j] *= alpha[i];
        }
        // PV: o[i][j] += sum_m P[r0+i][m] * V[m][c0+j]
#pragma unroll 8
        for (int mm = 0; mm < 64; ++mm) {
            float4 p4 = *(const float4*)&Pt[mm][r0];
            float4 v4 = *(const float4*)&KV[mm][c0];
            float a[4] = {p4.x, p4.y, p4.z, p4.w};
            float b[4] = {v4.x, v4.y, v4.z, v4.w};
#pragma unroll
            for (int i = 0; i < 4; ++i)
#pragma unroll
                for (int j = 0; j < 4; ++j)
                    o_acc[i][j] += a[i] * b[j];
        }
    }

    // epilogue: normalize and store
#pragma unroll
    for (int i = 0; i < 4; ++i) {
        float inv = 1.f / l_run[i];
        float4 ov;
        ov.x = o_acc[i][0] * inv;
        ov.y = o_acc[i][1] * inv;
        ov.z = o_acc[i][2] * inv;
        ov.w = o_acc[i][3] * inv;
        *(float4*)(O + (size_t)(n0 + r0 + i) * (NH * HDIM) + h * HDIM + c0) = ov;
    }
}

extern "C" void kernel_launch(void* const* d_in, const int* in_sizes, int n_in,
                              void* d_out, int out_size, void* d_ws, size_t ws_size,
                              hipStream_t stream) {
    const float* x  = (const float*)d_in[0];
    const float* fc = (const float*)d_in[1];
    const float* fs = (const float*)d_in[2];
    const float* Wq = (const float*)d_in[3];
    const float* Wk = (const float*)d_in[4];
    const float* Wv = (const float*)d_in[5];
    const float* Wo = (const float*)d_in[6];
    float* out = (float*)d_out;

    float* ws = (float*)d_ws;
    float* q  = ws;                                   // N_TOK * 1024
    float* k  = q  + (size_t)N_TOK * NH * HDIM;       // N_TOK * 256
    float* v  = k  + (size_t)N_TOK * NKV * HDIM;      // N_TOK * 256
    float* ao = v  + (size_t)N_TOK * NKV * HDIM;      // N_TOK * 1024

    dim3 blk(256);
    gemm64<true ><<<dim3(N_TOK / 64, (NH  * HDIM) / 64), blk, 0, stream>>>(x, Wq, q, DMODEL, NH  * HDIM, fc, fs);
    gemm64<true ><<<dim3(N_TOK / 64, (NKV * HDIM) / 64), blk, 0, stream>>>(x, Wk, k, DMODEL, NKV * HDIM, fc, fs);
    gemm64<false><<<dim3(N_TOK / 64, (NKV * HDIM) / 64), blk, 0, stream>>>(x, Wv, v, DMODEL, NKV * HDIM, nullptr, nullptr);
    attn64<<<dim3(N_TOK / 64, NH), blk, 0, stream>>>(q, k, v, ao);
    gemm64<false><<<dim3(N_TOK / 64, DMODEL / 64), blk, 0, stream>>>(ao, Wo, out, NH * HDIM, DMODEL, nullptr, nullptr);
}

// Round 2
// 193.730 us; speedup vs baseline: 3.2047x; 3.2047x over previous
//
#include <hip/hip_runtime.h>

#define N_TOK 2048
#define DMODEL 1024
#define NH 16
#define NKV 4
#define HDIM 64
#define SCALE_LOG2E 0.1803368801111204f  // (1/8) * log2(e)

typedef __attribute__((ext_vector_type(8))) short short8;
typedef __attribute__((ext_vector_type(4))) float f32x4;
typedef unsigned short u16;
typedef unsigned int u32;

__device__ __forceinline__ u16 f2bf(float x) {
    u32 u = __float_as_uint(x);
    u += 0x7FFF + ((u >> 16) & 1);   // round-to-nearest-even
    return (u16)(u >> 16);
}
__device__ __forceinline__ u32 pack2(float a, float b) {
    return (u32)f2bf(a) | ((u32)f2bf(b) << 16);
}

// ---------------------------------------------------------------------------
// prep: z=0..3 transpose W (K x NC) -> Wt (NC x K) bf16; z=4 convert x -> bf16
// grid (16,16,5), 256 threads
// ---------------------------------------------------------------------------
__global__ __launch_bounds__(256) void prep(
    const float* __restrict__ Wq, const float* __restrict__ Wk,
    const float* __restrict__ Wv, const float* __restrict__ Wo,
    const float* __restrict__ x,
    u16* __restrict__ Wqt, u16* __restrict__ Wkt, u16* __restrict__ Wvt,
    u16* __restrict__ Wot, u16* __restrict__ xb)
{
    const int z = blockIdx.z;
    const int t = threadIdx.x;
    if (z == 4) {
        size_t base = ((size_t)(blockIdx.y * 16 + blockIdx.x)) * 8192;
#pragma unroll
        for (int i = 0; i < 8; ++i) {
            float4 v = *(const float4*)(x + base + i * 1024 + t * 4);
            uint2 p; p.x = pack2(v.x, v.y); p.y = pack2(v.z, v.w);
            *(uint2*)(xb + base + i * 1024 + t * 4) = p;
        }
        return;
    }
    const float* W; u16* Wt; int NC;
    if      (z == 0) { W = Wq; Wt = Wqt; NC = 1024; }
    else if (z == 1) { W = Wk; Wt = Wkt; NC = 256; }
    else if (z == 2) { W = Wv; Wt = Wvt; NC = 256; }
    else             { W = Wo; Wt = Wot; NC = 1024; }
    const int n0 = blockIdx.x * 64;
    if (n0 >= NC) return;
    const int k0 = blockIdx.y * 64;
    __shared__ float T[64][68];
    const int row = t >> 2, cs = (t & 3) * 16;
#pragma unroll
    for (int i = 0; i < 4; ++i)
        *(float4*)&T[row][cs + i * 4] =
            *(const float4*)(W + (size_t)(k0 + row) * NC + n0 + cs + i * 4);
    __syncthreads();
    const int nl = t >> 2, ks = (t & 3) * 16;
    u32 pk[8];
#pragma unroll
    for (int i = 0; i < 8; ++i)
        pk[i] = pack2(T[ks + 2 * i][nl], T[ks + 2 * i + 1][nl]);
    u16* dst = Wt + (size_t)(n0 + nl) * DMODEL + k0 + ks;
    uint4 w0; w0.x = pk[0]; w0.y = pk[1]; w0.z = pk[2]; w0.w = pk[3];
    uint4 w1; w1.x = pk[4]; w1.y = pk[5]; w1.z = pk[6]; w1.w = pk[7];
    *(uint4*)(dst) = w0;
    *(uint4*)(dst + 8) = w1;
}

// ---------------------------------------------------------------------------
// MFMA GEMM: C(2048 x NC) = A(2048 x 1024)bf16 @ W(1024 x NC), W given as
// Wt(NC x 1024)bf16. Tile 128x128, BK=32, 4 waves of 64x64, 16x16x32 mfma.
// MODE 0: fused QKV (by<8 -> q rope bf16; by 8,9 -> k rope bf16; 10,11 -> vT)
// MODE 1: fp32 output (final projection)
// ---------------------------------------------------------------------------
template<int MODE>
__global__ __launch_bounds__(256, 2) void gemm_mfma(
    const u16* __restrict__ A,
    const u16* __restrict__ B0, const u16* __restrict__ B1, const u16* __restrict__ B2,
    u16* __restrict__ D0, u16* __restrict__ D1, u16* __restrict__ D2,
    float* __restrict__ Dout,
    const float* __restrict__ fc, const float* __restrict__ fs)
{
    __shared__ u16 As[128][40];
    __shared__ u16 Bs[128][40];
    const int t = threadIdx.x;
    const int m0 = blockIdx.x * 128;
    const int by = blockIdx.y;

    const u16* Bt; int nl0, ep;           // ep: 0 f32, 1 rope bf16, 2 vT
    u16* dbf = nullptr; int dstride = 0;
    if (MODE == 1) { Bt = B0; nl0 = by * 128; ep = 0; }
    else if (by < 8)  { Bt = B0; nl0 = by * 128;        dbf = D0; ep = 1; dstride = 1024; }
    else if (by < 10) { Bt = B1; nl0 = (by - 8) * 128;  dbf = D1; ep = 1; dstride = 256; }
    else              { Bt = B2; nl0 = (by - 10) * 128; dbf = D2; ep = 2; }

    const int w = t >> 6, lane = t & 63;
    const int quad = lane >> 4, l15 = lane & 15;
    const int wm = (w >> 1) * 64, wn = (w & 1) * 64;
    const int srow = t >> 1, sk = (t & 1) * 16;

    const u16* Ap = A + (size_t)(m0 + srow) * DMODEL + sk;
    const u16* Bp = Bt + (size_t)(nl0 + srow) * DMODEL + sk;

    f32x4 acc[4][4];
#pragma unroll
    for (int i = 0; i < 4; ++i)
#pragma unroll
        for (int j = 0; j < 4; ++j) acc[i][j] = {0.f, 0.f, 0.f, 0.f};

    uint4 ar0 = *(const uint4*)(Ap);
    uint4 ar1 = *(const uint4*)(Ap + 8);
    uint4 br0 = *(const uint4*)(Bp);
    uint4 br1 = *(const uint4*)(Bp + 8);

    for (int k0 = 0; k0 < DMODEL; k0 += 32) {
        __syncthreads();
        *(uint4*)&As[srow][sk]     = ar0;
        *(uint4*)&As[srow][sk + 8] = ar1;
        *(uint4*)&Bs[srow][sk]     = br0;
        *(uint4*)&Bs[srow][sk + 8] = br1;
        __syncthreads();
        if (k0 + 32 < DMODEL) {
            ar0 = *(const uint4*)(Ap + k0 + 32);
            ar1 = *(const uint4*)(Ap + k0 + 40);
            br0 = *(const uint4*)(Bp + k0 + 32);
            br1 = *(const uint4*)(Bp + k0 + 40);
        }
        short8 af[4], bf[4];
#pragma unroll
        for (int i = 0; i < 4; ++i)
            af[i] = *(const short8*)&As[wm + i * 16 + l15][quad * 8];
#pragma unroll
        for (int j = 0; j < 4; ++j)
            bf[j] = *(const short8*)&Bs[wn + j * 16 + l15][quad * 8];
#pragma unroll
        for (int i = 0; i < 4; ++i)
#pragma unroll
            for (int j = 0; j < 4; ++j)
                acc[i][j] = __builtin_amdgcn_mfma_f32_16x16x32_bf16(af[i], bf[j], acc[i][j], 0, 0, 0);
    }

    // epilogue: rows r = m0+wm+i*16+quad*4+r4, local col cl = nl0+wn+j*16+l15
#pragma unroll
    for (int i = 0; i < 4; ++i)
#pragma unroll
        for (int j = 0; j < 4; ++j) {
            const int cl = nl0 + wn + j * 16 + l15;
#pragma unroll
            for (int r4 = 0; r4 < 4; ++r4) {
                const int r = m0 + wm + i * 16 + quad * 4 + r4;
                float own = acc[i][j][r4];
                if (MODE == 1) {
                    Dout[(size_t)r * 1024 + cl] = own;
                } else if (ep == 1) {
                    float other = __shfl_xor(own, 1, 64);
                    const int p = (cl & 63) >> 1;
                    const float c = fc[r * 32 + p], s = fs[r * 32 + p];
                    float outv = ((cl & 1) == 0) ? (own * c - other * s)
                                                 : (other * s + own * c);
                    dbf[(size_t)r * dstride + cl] = f2bf(outv);
                } else if (ep == 2) {
                    dbf[(size_t)cl * N_TOK + r] = f2bf(own);
                }
            }
        }
}

// ---------------------------------------------------------------------------
// MFMA flash attention. Grid (32, 16) = (q-tile, head). 256 threads, 4 waves.
// Wave w handles q-rows [w*16, w*16+16) of the 64-row tile, all 64 keys/iter.
// Qb (2048x1024) bf16 rope'd, Kb (2048x256) bf16 rope'd, Vt (256x2048) bf16.
// ---------------------------------------------------------------------------
__global__ __launch_bounds__(256, 2) void attn(
    const u16* __restrict__ Qb, const u16* __restrict__ Kb,
    const u16* __restrict__ Vt, u16* __restrict__ Ob)
{
    __shared__ u16 Qs[64][72];
    __shared__ u16 Ks[64][72];
    __shared__ u16 Vs[64][72];   // [d][key]
    __shared__ u16 Ps[64][72];

    const int t = threadIdx.x;
    const int n0 = blockIdx.x * 64;
    const int h = blockIdx.y;
    const int kvh = h >> 2;
    const int w = t >> 6, lane = t & 63;
    const int quad = lane >> 4, l15 = lane & 15;
    const int srow = t >> 2, ssel = (t & 3) * 16;

    {   // stage Q tile (rows = tokens, cols = dims)
        const u16* qp = Qb + (size_t)(n0 + srow) * (NH * HDIM) + h * HDIM + ssel;
        *(uint4*)&Qs[srow][ssel]     = *(const uint4*)qp;
        *(uint4*)&Qs[srow][ssel + 8] = *(const uint4*)(qp + 8);
    }

    float m_run[4], l_run[4];
    f32x4 o[4];
#pragma unroll
    for (int i = 0; i < 4; ++i) { m_run[i] = -1e30f; l_run[i] = 0.f; o[i] = {0.f, 0.f, 0.f, 0.f}; }

    const int KSTRIDE = 64 * NKV * HDIM;
    const u16* kbase = Kb + (size_t)srow * (NKV * HDIM) + kvh * HDIM + ssel;
    const u16* vbase = Vt + (size_t)(kvh * HDIM + srow) * N_TOK + ssel;
    uint4 kr0 = *(const uint4*)(kbase);
    uint4 kr1 = *(const uint4*)(kbase + 8);
    uint4 vr0 = *(const uint4*)(vbase);
    uint4 vr1 = *(const uint4*)(vbase + 8);

    for (int kt = 0; kt < N_TOK / 64; ++kt) {
        __syncthreads();                      // prev PV reads of Ks/Vs done
        *(uint4*)&Ks[srow][ssel]     = kr0;   // K: [key][d]
        *(uint4*)&Ks[srow][ssel + 8] = kr1;
        *(uint4*)&Vs[srow][ssel]     = vr0;   // V: [d][key]
        *(uint4*)&Vs[srow][ssel + 8] = vr1;
        __syncthreads();                      // staging visible
        if (kt + 1 < N_TOK / 64) {
            kr0 = *(const uint4*)(kbase + (size_t)(kt + 1) * KSTRIDE);
            kr1 = *(const uint4*)(kbase + (size_t)(kt + 1) * KSTRIDE + 8);
            vr0 = *(const uint4*)(vbase + (kt + 1) * 64);
            vr1 = *(const uint4*)(vbase + (kt + 1) * 64 + 8);
        }
        // ---- S = Q K^T (per-wave 16q x 64k) ----
        short8 aq0 = *(const short8*)&Qs[w * 16 + l15][quad * 8];
        short8 aq1 = *(const short8*)&Qs[w * 16 + l15][quad * 8 + 32];
        f32x4 s[4];
#pragma unroll
        for (int nt = 0; nt < 4; ++nt) {
            f32x4 z = {0.f, 0.f, 0.f, 0.f};
            short8 b0 = *(const short8*)&Ks[nt * 16 + l15][quad * 8];
            short8 b1 = *(const short8*)&Ks[nt * 16 + l15][quad * 8 + 32];
            z = __builtin_amdgcn_mfma_f32_16x16x32_bf16(aq0, b0, z, 0, 0, 0);
            z = __builtin_amdgcn_mfma_f32_16x16x32_bf16(aq1, b1, z, 0, 0, 0);
            s[nt] = z * SCALE_LOG2E;          // fold scale*log2(e)
        }
        // ---- online softmax (rows = quad*4+r; 16 lanes of quad share a row) ----
        float alpha[4];
#pragma unroll
        for (int r = 0; r < 4; ++r) {
            float v = fmaxf(fmaxf(s[0][r], s[1][r]), fmaxf(s[2][r], s[3][r]));
#pragma unroll
            for (int d = 1; d < 16; d <<= 1) v = fmaxf(v, __shfl_xor(v, d, 64));
            float mnew = fmaxf(m_run[r], v);
            alpha[r] = __builtin_amdgcn_exp2f(m_run[r] - mnew);
            m_run[r] = mnew;
        }
        float lsum[4] = {0.f, 0.f, 0.f, 0.f};
        u16 pb[4][4];
#pragma unroll
        for (int nt = 0; nt < 4; ++nt)
#pragma unroll
            for (int r = 0; r < 4; ++r) {
                float p = __builtin_amdgcn_exp2f(s[nt][r] - m_run[r]);
                lsum[r] += p;
                pb[nt][r] = f2bf(p);
            }
#pragma unroll
        for (int r = 0; r < 4; ++r) {
            float v = lsum[r];
#pragma unroll
            for (int d = 1; d < 16; d <<= 1) v += __shfl_xor(v, d, 64);
            l_run[r] = l_run[r] * alpha[r] + v;
        }
#pragma unroll
        for (int nt = 0; nt < 4; ++nt)
#pragma unroll
            for (int r = 0; r < 4; ++r)
                Ps[w * 16 + quad * 4 + r][nt * 16 + l15] = pb[nt][r];
#pragma unroll
        for (int nt = 0; nt < 4; ++nt)
#pragma unroll
            for (int r = 0; r < 4; ++r) o[nt][r] *= alpha[r];
        __syncthreads();                      // P visible (and lgkm drained)
        // ---- O += P V ----
        short8 ap0 = *(const short8*)&Ps[w * 16 + l15][quad * 8];
        short8 ap1 = *(const short8*)&Ps[w * 16 + l15][quad * 8 + 32];
#pragma unroll
        for (int nt = 0; nt < 4; ++nt) {
            short8 b0 = *(const short8*)&Vs[nt * 16 + l15][quad * 8];
            short8 b1 = *(const short8*)&Vs[nt * 16 + l15][quad * 8 + 32];
            o[nt] = __builtin_amdgcn_mfma_f32_16x16x32_bf16(ap0, b0, o[nt], 0, 0, 0);
            o[nt] = __builtin_amdgcn_mfma_f32_16x16x32_bf16(ap1, b1, o[nt], 0, 0, 0);
        }
    }
    // epilogue
#pragma unroll
    for (int nt = 0; nt < 4; ++nt)
#pragma unroll
        for (int r = 0; r < 4; ++r) {
            const int qrow = n0 + w * 16 + quad * 4 + r;
            const int col = h * HDIM + nt * 16 + l15;
            Ob[(size_t)qrow * (NH * HDIM) + col] = f2bf(o[nt][r] / l_run[r]);
        }
}

// ---------------------------------------------------------------------------
extern "C" void kernel_launch(void* const* d_in, const int* in_sizes, int n_in,
                              void* d_out, int out_size, void* d_ws, size_t ws_size,
                              hipStream_t stream) {
    const float* x  = (const float*)d_in[0];
    const float* fc = (const float*)d_in[1];
    const float* fs = (const float*)d_in[2];
    const float* Wq = (const float*)d_in[3];
    const float* Wk = (const float*)d_in[4];
    const float* Wv = (const float*)d_in[5];
    const float* Wo = (const float*)d_in[6];
    float* out = (float*)d_out;

    u16* ws  = (u16*)d_ws;
    u16* xb  = ws;                       // 2048*1024
    u16* Wqt = xb  + (size_t)2048 * 1024;  // 1024*1024
    u16* Wkt = Wqt + (size_t)1024 * 1024;  // 256*1024
    u16* Wvt = Wkt + (size_t)256 * 1024;   // 256*1024
    u16* Wot = Wvt + (size_t)256 * 1024;   // 1024*1024
    u16* qb  = Wot + (size_t)1024 * 1024;  // 2048*1024
    u16* kb  = qb  + (size_t)2048 * 1024;  // 2048*256
    u16* vT  = kb  + (size_t)2048 * 256;   // 256*2048
    u16* aob = vT  + (size_t)256 * 2048;   // 2048*1024

    dim3 blk(256);
    prep<<<dim3(16, 16, 5), blk, 0, stream>>>(Wq, Wk, Wv, Wo, x, Wqt, Wkt, Wvt, Wot, xb);
    gemm_mfma<0><<<dim3(16, 12), blk, 0, stream>>>(xb, Wqt, Wkt, Wvt, qb, kb, vT,
                                                   nullptr, fc, fs);
    attn<<<dim3(32, 16), blk, 0, stream>>>(qb, kb, vT, aob);
    gemm_mfma<1><<<dim3(16, 8), blk, 0, stream>>>(aob, Wot, nullptr, nullptr,
                                                  nullptr, nullptr, nullptr, out, fc, fs);
}